// Round 1
// baseline (1409.434 us; speedup 1.0000x reference)
//
#include <hip/hip_runtime.h>
#include <math.h>

#define NN 100000
#define NE 3200000
#define FIN 128
#define HID 64
#define NC 7

__device__ __forceinline__ float readlane_f(float v, int lane) {
    return __int_as_float(__builtin_amdgcn_readlane(__float_as_int(v), lane));
}

// ---------------- degree: cnt[d] += 1 ----------------
__global__ __launch_bounds__(256) void k_degree(const int* __restrict__ dst,
                                                float* __restrict__ cnt) {
    int e = blockIdx.x * 256 + threadIdx.x;
    if (e < NE) atomicAdd(&cnt[dst[e]], 1.0f);
}

// ---------------- proj1: p1 = x @ W1_l^T, r1 = x @ W1_r^T ----------------
// Block 256 = 4 waves; each wave computes 4 nodes; lane l = output channel.
// W interleaved in LDS: Wc[k][2j] = Wl[j][k], Wc[k][2j+1] = Wr[j][k] (64 KB).
__global__ __launch_bounds__(256) void k_proj1(const float* __restrict__ x,
                                               const float* __restrict__ Wl,
                                               const float* __restrict__ Wr,
                                               float* __restrict__ p1,
                                               float* __restrict__ r1) {
    __shared__ float Wc[128 * 128];
    int tid = threadIdx.x;
    for (int t = tid; t < 64 * 128; t += 256) {
        int j = t & 63;        // output channel 0..63
        int k = t >> 6;        // input channel 0..127
        Wc[k * 128 + 2 * j]     = Wl[j * 128 + k];
        Wc[k * 128 + 2 * j + 1] = Wr[j * 128 + k];
    }
    __syncthreads();
    int wave = tid >> 6;
    int l = tid & 63;
    // NN % 16 == 0, so no tail guards needed.
    for (int base = blockIdx.x * 16 + wave * 4; base < NN; base += gridDim.x * 16) {
        float xa[4], xb[4], ap[4], ar[4];
#pragma unroll
        for (int i = 0; i < 4; ++i) {
            int n = base + i;
            xa[i] = x[n * 128 + l];
            xb[i] = x[n * 128 + 64 + l];
            ap[i] = 0.f; ar[i] = 0.f;
        }
#pragma unroll
        for (int k = 0; k < 128; ++k) {
            float2 w = *(const float2*)&Wc[k * 128 + 2 * l];
#pragma unroll
            for (int i = 0; i < 4; ++i) {
                float xk = readlane_f(k < 64 ? xa[i] : xb[i], k & 63);
                ap[i] = fmaf(xk, w.x, ap[i]);
                ar[i] = fmaf(xk, w.y, ar[i]);
            }
        }
#pragma unroll
        for (int i = 0; i < 4; ++i) {
            int n = base + i;
            p1[n * 64 + l] = ap[i];
            r1[n * 64 + l] = ar[i];
        }
    }
}

// ---------------- scatter1: agg1[d][k] += p1[s][k] ----------------
// One wave per edge (64 lanes = 64 channels): fully coalesced 256B row ops.
__global__ __launch_bounds__(256) void k_scatter1(const int* __restrict__ src,
                                                  const int* __restrict__ dst,
                                                  const float* __restrict__ p1,
                                                  float* __restrict__ agg1) {
    int tid = blockIdx.x * 256 + threadIdx.x;
    int e = tid >> 6;
    int k = tid & 63;
    if (e < NE) {
        int s = src[e];
        int d = dst[e];
        atomicAdd(&agg1[d * 64 + k], p1[s * 64 + k]);
    }
}

// ---------------- combine1 + proj2 (fused) ----------------
// h = relu(agg1/cnt + r1 + b1) in registers; p2 = h@W2l^T, r2 = h@W2r^T.
__global__ __launch_bounds__(256) void k_combine1(const float* __restrict__ agg1,
                                                  const float* __restrict__ r1,
                                                  const float* __restrict__ cnt,
                                                  const float* __restrict__ b1,
                                                  const float* __restrict__ W2l,
                                                  const float* __restrict__ W2r,
                                                  float* __restrict__ p2,
                                                  float* __restrict__ r2) {
    __shared__ float sWl[NC * HID];
    __shared__ float sWr[NC * HID];
    __shared__ float sb[HID];
    int tid = threadIdx.x;
    for (int t = tid; t < NC * HID; t += 256) {
        sWl[t] = W2l[t];
        sWr[t] = W2r[t];
    }
    if (tid < HID) sb[tid] = b1[tid];
    __syncthreads();
    int n = blockIdx.x * 256 + tid;
    if (n >= NN) return;
    float inv = 1.0f / fmaxf(cnt[n], 1.0f);
    float ap[NC], ar[NC];
#pragma unroll
    for (int c = 0; c < NC; ++c) { ap[c] = 0.f; ar[c] = 0.f; }
    const float4* A = (const float4*)(agg1 + (size_t)n * HID);
    const float4* R = (const float4*)(r1 + (size_t)n * HID);
#pragma unroll
    for (int q = 0; q < HID / 4; ++q) {
        float4 a = A[q];
        float4 r = R[q];
        float h0 = fmaxf(a.x * inv + r.x + sb[4 * q + 0], 0.f);
        float h1 = fmaxf(a.y * inv + r.y + sb[4 * q + 1], 0.f);
        float h2 = fmaxf(a.z * inv + r.z + sb[4 * q + 2], 0.f);
        float h3 = fmaxf(a.w * inv + r.w + sb[4 * q + 3], 0.f);
#pragma unroll
        for (int c = 0; c < NC; ++c) {
            float4 wl = *(const float4*)&sWl[c * HID + 4 * q];
            float4 wr = *(const float4*)&sWr[c * HID + 4 * q];
            ap[c] += h0 * wl.x + h1 * wl.y + h2 * wl.z + h3 * wl.w;
            ar[c] += h0 * wr.x + h1 * wr.y + h2 * wr.z + h3 * wr.w;
        }
    }
#pragma unroll
    for (int c = 0; c < NC; ++c) {
        p2[n * NC + c] = ap[c];
        r2[n * NC + c] = ar[c];
    }
}

// ---------------- scatter2: agg2[d][c] += p2[s][c] ----------------
// 8 lanes per edge (lane 7 idle).
__global__ __launch_bounds__(256) void k_scatter2(const int* __restrict__ src,
                                                  const int* __restrict__ dst,
                                                  const float* __restrict__ p2,
                                                  float* __restrict__ agg2) {
    int tid = blockIdx.x * 256 + threadIdx.x;
    int e = tid >> 3;
    int c = tid & 7;
    if (e < NE && c < NC) {
        int s = src[e];
        int d = dst[e];
        atomicAdd(&agg2[d * NC + c], p2[s * NC + c]);
    }
}

// ---------------- final: out = log_softmax(agg2/cnt + r2 + b2) ----------------
__global__ __launch_bounds__(256) void k_final(const float* __restrict__ agg2,
                                               const float* __restrict__ r2,
                                               const float* __restrict__ cnt,
                                               const float* __restrict__ b2,
                                               float* __restrict__ out) {
    int n = blockIdx.x * 256 + threadIdx.x;
    if (n >= NN) return;
    float inv = 1.0f / fmaxf(cnt[n], 1.0f);
    float v[NC];
    float m = -INFINITY;
#pragma unroll
    for (int c = 0; c < NC; ++c) {
        v[c] = agg2[n * NC + c] * inv + r2[n * NC + c] + b2[c];
        m = fmaxf(m, v[c]);
    }
    float s = 0.f;
#pragma unroll
    for (int c = 0; c < NC; ++c) s += expf(v[c] - m);
    float ls = logf(s);
#pragma unroll
    for (int c = 0; c < NC; ++c) out[n * NC + c] = v[c] - m - ls;
}

extern "C" void kernel_launch(void* const* d_in, const int* in_sizes, int n_in,
                              void* d_out, int out_size, void* d_ws, size_t ws_size,
                              hipStream_t stream) {
    const float* x   = (const float*)d_in[0];
    const int*   ei  = (const int*)d_in[1];   // [2, NE] int32
    const float* W1l = (const float*)d_in[2];
    const float* W1r = (const float*)d_in[3];
    const float* b1  = (const float*)d_in[4];
    const float* W2l = (const float*)d_in[5];
    const float* W2r = (const float*)d_in[6];
    const float* b2  = (const float*)d_in[7];
    float* out = (float*)d_out;

    const int* src = ei;
    const int* dst = ei + NE;

    float* ws   = (float*)d_ws;
    float* cnt  = ws;                       // NN
    float* p1   = ws + 100000;              // NN*64
    float* r1   = p1 + (size_t)NN * HID;    // NN*64
    float* agg1 = r1 + (size_t)NN * HID;    // NN*64
    float* p2   = agg1 + (size_t)NN * HID;  // NN*7
    float* r2   = p2 + (size_t)NN * NC;     // NN*7
    float* agg2 = r2 + (size_t)NN * NC;     // NN*7

    hipMemsetAsync(cnt, 0, (size_t)NN * sizeof(float), stream);
    hipMemsetAsync(agg1, 0, (size_t)NN * HID * sizeof(float), stream);
    hipMemsetAsync(agg2, 0, (size_t)NN * NC * sizeof(float), stream);

    k_degree<<<(NE + 255) / 256, 256, 0, stream>>>(dst, cnt);
    k_proj1<<<512, 256, 0, stream>>>(x, W1l, W1r, p1, r1);
    k_scatter1<<<(NE * 64) / 256, 256, 0, stream>>>(src, dst, p1, agg1);
    k_combine1<<<(NN + 255) / 256, 256, 0, stream>>>(agg1, r1, cnt, b1, W2l, W2r, p2, r2);
    k_scatter2<<<(NE * 8) / 256, 256, 0, stream>>>(src, dst, p2, agg2);
    k_final<<<(NN + 255) / 256, 256, 0, stream>>>(agg2, r2, cnt, b2, out);
}

// Round 2
// 900.706 us; speedup vs baseline: 1.5648x; 1.5648x over previous
//
#include <hip/hip_runtime.h>
#include <math.h>

#define NN 100000
#define NE 3200000
#define FIN 128
#define HID 64
#define NC 7
#define NB 391   // ceil(NN/256)

__device__ __forceinline__ float readlane_f(float v, int lane) {
    return __int_as_float(__builtin_amdgcn_readlane(__float_as_int(v), lane));
}

// ---------------- histogram: cnti[d]++ ----------------
__global__ __launch_bounds__(256) void k_hist(const int* __restrict__ dst,
                                              int* __restrict__ cnti) {
    int e = blockIdx.x * 256 + threadIdx.x;
    if (e < NE) atomicAdd(&cnti[dst[e]], 1);
}

// ---------------- scan step 1: per-block sums ----------------
__global__ __launch_bounds__(256) void k_bsum(const int* __restrict__ cnti,
                                              int* __restrict__ bsum) {
    int n = blockIdx.x * 256 + threadIdx.x;
    int v = (n < NN) ? cnti[n] : 0;
#pragma unroll
    for (int d = 32; d; d >>= 1) v += __shfl_xor(v, d);
    __shared__ int w4[4];
    if ((threadIdx.x & 63) == 0) w4[threadIdx.x >> 6] = v;
    __syncthreads();
    if (threadIdx.x == 0) bsum[blockIdx.x] = w4[0] + w4[1] + w4[2] + w4[3];
}

// ---------------- scan step 2: exclusive scan of block sums (1 block) -------
__global__ __launch_bounds__(512) void k_bscan(const int* __restrict__ bsum,
                                               int* __restrict__ boff) {
    __shared__ int s[512];
    int t = threadIdx.x;
    int v = (t < NB) ? bsum[t] : 0;
    s[t] = v;
    __syncthreads();
    for (int d = 1; d < 512; d <<= 1) {
        int add = (t >= d) ? s[t - d] : 0;
        __syncthreads();
        s[t] += add;
        __syncthreads();
    }
    if (t < NB) boff[t] = s[t] - v;  // exclusive
}

// ---------------- scan step 3: per-element exclusive scan + block offset ----
__global__ __launch_bounds__(256) void k_scan3(const int* __restrict__ cnti,
                                               const int* __restrict__ boff,
                                               int* __restrict__ offs,
                                               int* __restrict__ cur) {
    __shared__ int s[256];
    int b = blockIdx.x, t = threadIdx.x;
    int n = b * 256 + t;
    int v = (n < NN) ? cnti[n] : 0;
    s[t] = v;
    __syncthreads();
    for (int d = 1; d < 256; d <<= 1) {
        int add = (t >= d) ? s[t - d] : 0;
        __syncthreads();
        s[t] += add;
        __syncthreads();
    }
    if (n < NN) {
        int o = boff[b] + s[t] - v;
        offs[n] = o;
        cur[n] = o;
    }
}

// ---------------- counting-sort pass: skey[pos] = src, grouped by dst -------
__global__ __launch_bounds__(256) void k_sort(const int* __restrict__ src,
                                              const int* __restrict__ dst,
                                              int* __restrict__ cur,
                                              int* __restrict__ skey) {
    int e = blockIdx.x * 256 + threadIdx.x;
    if (e < NE) {
        int d = dst[e];
        int p = atomicAdd(&cur[d], 1);
        skey[p] = src[e];
    }
}

// ---------------- proj1: p1 = x @ W1_l^T, r1 = x @ W1_r^T ----------------
__global__ __launch_bounds__(256) void k_proj1(const float* __restrict__ x,
                                               const float* __restrict__ Wl,
                                               const float* __restrict__ Wr,
                                               float* __restrict__ p1,
                                               float* __restrict__ r1) {
    __shared__ float Wc[128 * 128];
    int tid = threadIdx.x;
    for (int t = tid; t < 64 * 128; t += 256) {
        int j = t & 63;
        int k = t >> 6;
        Wc[k * 128 + 2 * j]     = Wl[j * 128 + k];
        Wc[k * 128 + 2 * j + 1] = Wr[j * 128 + k];
    }
    __syncthreads();
    int wave = tid >> 6;
    int l = tid & 63;
    for (int base = blockIdx.x * 16 + wave * 4; base < NN; base += gridDim.x * 16) {
        float xa[4], xb[4], ap[4], ar[4];
#pragma unroll
        for (int i = 0; i < 4; ++i) {
            int n = base + i;
            xa[i] = x[n * 128 + l];
            xb[i] = x[n * 128 + 64 + l];
            ap[i] = 0.f; ar[i] = 0.f;
        }
#pragma unroll
        for (int k = 0; k < 128; ++k) {
            float2 w = *(const float2*)&Wc[k * 128 + 2 * l];
#pragma unroll
            for (int i = 0; i < 4; ++i) {
                float xk = readlane_f(k < 64 ? xa[i] : xb[i], k & 63);
                ap[i] = fmaf(xk, w.x, ap[i]);
                ar[i] = fmaf(xk, w.y, ar[i]);
            }
        }
#pragma unroll
        for (int i = 0; i < 4; ++i) {
            int n = base + i;
            p1[n * 64 + l] = ap[i];
            r1[n * 64 + l] = ar[i];
        }
    }
}

// ---- agg1 + combine1 + proj2 fused: wave per node, lane = channel ----
// h = relu(mean_gather(p1) + r1 + b1); p2 = h@W2l^T, r2 = h@W2r^T via
// wave reductions.
__global__ __launch_bounds__(256) void k_agg1c(const float* __restrict__ p1,
                                               const float* __restrict__ r1,
                                               const int* __restrict__ skey,
                                               const int* __restrict__ offs,
                                               const int* __restrict__ cnti,
                                               const float* __restrict__ b1,
                                               const float* __restrict__ W2l,
                                               const float* __restrict__ W2r,
                                               float* __restrict__ p2,
                                               float* __restrict__ r2) {
    int n = (blockIdx.x * 256 + threadIdx.x) >> 6;
    int l = threadIdx.x & 63;
    if (n >= NN) return;
    int off = offs[n];
    int dc = cnti[n];
    int i = off, end = off + dc;
    float acc = 0.f;
    for (; i + 3 < end; i += 4) {
        int s0 = skey[i], s1 = skey[i + 1], s2 = skey[i + 2], s3 = skey[i + 3];
        acc += p1[(size_t)s0 * 64 + l];
        acc += p1[(size_t)s1 * 64 + l];
        acc += p1[(size_t)s2 * 64 + l];
        acc += p1[(size_t)s3 * 64 + l];
    }
    for (; i < end; ++i) acc += p1[(size_t)skey[i] * 64 + l];
    float inv = (dc > 0) ? 1.f / (float)dc : 0.f;
    float h = fmaxf(acc * inv + r1[(size_t)n * 64 + l] + b1[l], 0.f);

    float pv[NC], rv[NC];
#pragma unroll
    for (int c = 0; c < NC; ++c) {
        float a = h * W2l[c * 64 + l];
        float b = h * W2r[c * 64 + l];
#pragma unroll
        for (int d = 32; d; d >>= 1) {
            a += __shfl_xor(a, d);
            b += __shfl_xor(b, d);
        }
        pv[c] = a; rv[c] = b;
    }
    // lane c writes channel c (static-index selection, no scratch)
    float po = 0.f, ro = 0.f;
#pragma unroll
    for (int c = 0; c < NC; ++c) {
        po = (l == c) ? pv[c] : po;
        ro = (l == c) ? rv[c] : ro;
    }
    if (l < NC) {
        p2[(size_t)n * NC + l] = po;
        r2[(size_t)n * NC + l] = ro;
    }
}

// ---- agg2 + bias + log_softmax fused: 8 lanes per node (lane 7 idle) ----
__global__ __launch_bounds__(256) void k_agg2f(const float* __restrict__ p2,
                                               const float* __restrict__ r2,
                                               const int* __restrict__ skey,
                                               const int* __restrict__ offs,
                                               const int* __restrict__ cnti,
                                               const float* __restrict__ b2,
                                               float* __restrict__ out) {
    int tid = blockIdx.x * 256 + threadIdx.x;
    int n = tid >> 3;
    int c = tid & 7;
    if (n >= NN) return;
    bool act = (c < NC);
    int off = offs[n];
    int dc = cnti[n];
    int i = off, end = off + dc;
    float acc = 0.f;
    for (; i + 3 < end; i += 4) {
        int s0 = skey[i], s1 = skey[i + 1], s2 = skey[i + 2], s3 = skey[i + 3];
        if (act) {
            acc += p2[(size_t)s0 * NC + c];
            acc += p2[(size_t)s1 * NC + c];
            acc += p2[(size_t)s2 * NC + c];
            acc += p2[(size_t)s3 * NC + c];
        }
    }
    for (; i < end; ++i) if (act) acc += p2[(size_t)skey[i] * NC + c];
    float inv = (dc > 0) ? 1.f / (float)dc : 0.f;
    float v = act ? (acc * inv + r2[(size_t)n * NC + c] + b2[c]) : -INFINITY;
    float m = v;
#pragma unroll
    for (int d = 1; d < 8; d <<= 1) m = fmaxf(m, __shfl_xor(m, d));
    float ev = act ? expf(v - m) : 0.f;
    float s = ev;
#pragma unroll
    for (int d = 1; d < 8; d <<= 1) s += __shfl_xor(s, d);
    if (act) out[(size_t)n * NC + c] = v - m - logf(s);
}

extern "C" void kernel_launch(void* const* d_in, const int* in_sizes, int n_in,
                              void* d_out, int out_size, void* d_ws, size_t ws_size,
                              hipStream_t stream) {
    const float* x   = (const float*)d_in[0];
    const int*   ei  = (const int*)d_in[1];   // [2, NE] int32
    const float* W1l = (const float*)d_in[2];
    const float* W1r = (const float*)d_in[3];
    const float* b1  = (const float*)d_in[4];
    const float* W2l = (const float*)d_in[5];
    const float* W2r = (const float*)d_in[6];
    const float* b2  = (const float*)d_in[7];
    float* out = (float*)d_out;

    const int* src = ei;
    const int* dst = ei + NE;

    // workspace layout (4-byte units), total ~70.8 MB
    int* cnti = (int*)d_ws;             // NN
    int* offs = cnti + NN;              // NN
    int* cur  = offs + NN;              // NN
    int* bsum = cur + NN;               // 512
    int* boff = bsum + 512;             // 512
    int* skey = boff + 512;             // NE
    float* p1 = (float*)(skey + NE);    // NN*64
    float* r1 = p1 + (size_t)NN * HID;  // NN*64
    float* p2 = r1 + (size_t)NN * HID;  // NN*7
    float* r2 = p2 + (size_t)NN * NC;   // NN*7

    hipMemsetAsync(cnti, 0, (size_t)NN * sizeof(int), stream);

    k_hist <<<(NE + 255) / 256, 256, 0, stream>>>(dst, cnti);
    k_bsum <<<NB, 256, 0, stream>>>(cnti, bsum);
    k_bscan<<<1, 512, 0, stream>>>(bsum, boff);
    k_scan3<<<NB, 256, 0, stream>>>(cnti, boff, offs, cur);
    k_sort <<<(NE + 255) / 256, 256, 0, stream>>>(src, dst, cur, skey);
    k_proj1<<<512, 256, 0, stream>>>(x, W1l, W1r, p1, r1);
    k_agg1c<<<(NN * 64 + 255) / 256, 256, 0, stream>>>(p1, r1, skey, offs, cnti,
                                                       b1, W2l, W2r, p2, r2);
    k_agg2f<<<(NN * 8 + 255) / 256, 256, 0, stream>>>(p2, r2, skey, offs, cnti,
                                                      b2, out);
}

// Round 3
// 621.329 us; speedup vs baseline: 2.2684x; 1.4496x over previous
//
#include <hip/hip_runtime.h>
#include <math.h>

#define NN 100000
#define NE 3200000
#define FIN 128
#define HID 64
#define NC 7
#define NB 391   // ceil(NN/256)

// ---------------- histogram: cnti[d]++ ----------------
__global__ __launch_bounds__(256) void k_hist(const int* __restrict__ dst,
                                              int* __restrict__ cnti) {
    int e = blockIdx.x * 256 + threadIdx.x;
    if (e < NE) atomicAdd(&cnti[dst[e]], 1);
}

// ---------------- scan step 1: per-block sums ----------------
__global__ __launch_bounds__(256) void k_bsum(const int* __restrict__ cnti,
                                              int* __restrict__ bsum) {
    int n = blockIdx.x * 256 + threadIdx.x;
    int v = (n < NN) ? cnti[n] : 0;
#pragma unroll
    for (int d = 32; d; d >>= 1) v += __shfl_xor(v, d);
    __shared__ int w4[4];
    if ((threadIdx.x & 63) == 0) w4[threadIdx.x >> 6] = v;
    __syncthreads();
    if (threadIdx.x == 0) bsum[blockIdx.x] = w4[0] + w4[1] + w4[2] + w4[3];
}

// ---------------- scan step 2: exclusive scan of block sums (1 block) -------
__global__ __launch_bounds__(512) void k_bscan(const int* __restrict__ bsum,
                                               int* __restrict__ boff) {
    __shared__ int s[512];
    int t = threadIdx.x;
    int v = (t < NB) ? bsum[t] : 0;
    s[t] = v;
    __syncthreads();
    for (int d = 1; d < 512; d <<= 1) {
        int add = (t >= d) ? s[t - d] : 0;
        __syncthreads();
        s[t] += add;
        __syncthreads();
    }
    if (t < NB) boff[t] = s[t] - v;  // exclusive
}

// ---------------- scan step 3: per-element exclusive scan + block offset ----
__global__ __launch_bounds__(256) void k_scan3(const int* __restrict__ cnti,
                                               const int* __restrict__ boff,
                                               int* __restrict__ offs,
                                               int* __restrict__ cur) {
    __shared__ int s[256];
    int b = blockIdx.x, t = threadIdx.x;
    int n = b * 256 + t;
    int v = (n < NN) ? cnti[n] : 0;
    s[t] = v;
    __syncthreads();
    for (int d = 1; d < 256; d <<= 1) {
        int add = (t >= d) ? s[t - d] : 0;
        __syncthreads();
        s[t] += add;
        __syncthreads();
    }
    if (n < NN) {
        int o = boff[b] + s[t] - v;
        offs[n] = o;
        cur[n] = o;
    }
}

// ---------------- counting-sort pass: skey[pos] = src, grouped by dst -------
__global__ __launch_bounds__(256) void k_sort(const int* __restrict__ src,
                                              const int* __restrict__ dst,
                                              int* __restrict__ cur,
                                              int* __restrict__ skey) {
    int e = blockIdx.x * 256 + threadIdx.x;
    if (e < NE) {
        int d = dst[e];
        int p = atomicAdd(&cur[d], 1);
        skey[p] = src[e];
    }
}

// ---------------- W transpose: Wt[k][j] = (j<64 ? Wl[j][k] : Wr[j-64][k]) ---
__global__ __launch_bounds__(256) void k_wt(const float* __restrict__ Wl,
                                            const float* __restrict__ Wr,
                                            float* __restrict__ Wt) {
    int t = blockIdx.x * 256 + threadIdx.x;
    if (t < 128 * 128) {
        int k = t >> 7, j = t & 127;
        Wt[t] = (j < 64) ? Wl[j * 128 + k] : Wr[(j - 64) * 128 + k];
    }
}

// ---------------- proj1: register-tiled SGEMM ----------------
// Y[128 nodes][128 ch] per block; ch 0..63 -> p1, 64..127 -> r1.
// 256 threads, each an 8x8 micro-tile. BK=16, single-buffered LDS.
__global__ __launch_bounds__(256) void k_proj1(const float* __restrict__ x,
                                               const float* __restrict__ Wt,
                                               float* __restrict__ p1,
                                               float* __restrict__ r1) {
    __shared__ float xs[16][132];  // [kk][node], +4 pad: conflict-free & 16B-aligned
    __shared__ float ws[16][128];  // [kk][ch]
    int t = threadIdx.x;
    int tm = t >> 4;   // 0..15 (node group)
    int tn = t & 15;   // 0..15 (channel group)
    int n0 = blockIdx.x * 128;

    float acc[8][8];
#pragma unroll
    for (int i = 0; i < 8; ++i)
#pragma unroll
        for (int j = 0; j < 8; ++j) acc[i][j] = 0.f;

    for (int k0 = 0; k0 < 128; k0 += 16) {
        // stage xs (transposed): 128 nodes x 16 k = 512 float4s, 2 per thread
#pragma unroll
        for (int p = 0; p < 2; ++p) {
            int fid = p * 256 + t;
            int node = fid >> 2;      // 0..127
            int q = fid & 3;          // which float4 of the 16-k chunk
            float4 v = make_float4(0.f, 0.f, 0.f, 0.f);
            if (n0 + node < NN)
                v = *(const float4*)&x[(size_t)(n0 + node) * 128 + k0 + q * 4];
            xs[q * 4 + 0][node] = v.x;
            xs[q * 4 + 1][node] = v.y;
            xs[q * 4 + 2][node] = v.z;
            xs[q * 4 + 3][node] = v.w;
        }
        // stage ws: 16 k x 128 ch = 512 float4s, 2 per thread
#pragma unroll
        for (int p = 0; p < 2; ++p) {
            int fid = p * 256 + t;
            int kk = fid >> 5;        // 0..15
            int jq = fid & 31;        // float4 index within row
            *(float4*)&ws[kk][jq * 4] =
                *(const float4*)&Wt[(size_t)(k0 + kk) * 128 + jq * 4];
        }
        __syncthreads();
#pragma unroll
        for (int kk = 0; kk < 16; ++kk) {
            float4 a0 = *(const float4*)&xs[kk][tm * 8];
            float4 a1 = *(const float4*)&xs[kk][tm * 8 + 4];
            float4 b0 = *(const float4*)&ws[kk][tn * 8];
            float4 b1 = *(const float4*)&ws[kk][tn * 8 + 4];
            float a[8] = {a0.x, a0.y, a0.z, a0.w, a1.x, a1.y, a1.z, a1.w};
            float b[8] = {b0.x, b0.y, b0.z, b0.w, b1.x, b1.y, b1.z, b1.w};
#pragma unroll
            for (int i = 0; i < 8; ++i)
#pragma unroll
                for (int j = 0; j < 8; ++j)
                    acc[i][j] = fmaf(a[i], b[j], acc[i][j]);
        }
        __syncthreads();
    }
    // store: thread covers nodes n0+tm*8..+7, channels tn*8..+7
#pragma unroll
    for (int i = 0; i < 8; ++i) {
        int n = n0 + tm * 8 + i;
        if (n >= NN) break;
        float4 v0 = make_float4(acc[i][0], acc[i][1], acc[i][2], acc[i][3]);
        float4 v1 = make_float4(acc[i][4], acc[i][5], acc[i][6], acc[i][7]);
        if (tn < 8) {
            *(float4*)&p1[(size_t)n * 64 + tn * 8]     = v0;
            *(float4*)&p1[(size_t)n * 64 + tn * 8 + 4] = v1;
        } else {
            *(float4*)&r1[(size_t)n * 64 + (tn - 8) * 8]     = v0;
            *(float4*)&r1[(size_t)n * 64 + (tn - 8) * 8 + 4] = v1;
        }
    }
}

// ---- agg1 + combine1 + proj2 fused: wave per node, lane = channel ----
__global__ __launch_bounds__(256) void k_agg1c(const float* __restrict__ p1,
                                               const float* __restrict__ r1,
                                               const int* __restrict__ skey,
                                               const int* __restrict__ offs,
                                               const int* __restrict__ cnti,
                                               const float* __restrict__ b1,
                                               const float* __restrict__ W2l,
                                               const float* __restrict__ W2r,
                                               float* __restrict__ p2,
                                               float* __restrict__ r2) {
    int n = (blockIdx.x * 256 + threadIdx.x) >> 6;
    int l = threadIdx.x & 63;
    if (n >= NN) return;
    int off = offs[n];
    int dc = cnti[n];
    int i = off, end = off + dc;
    float acc = 0.f;
    for (; i + 3 < end; i += 4) {
        int s0 = skey[i], s1 = skey[i + 1], s2 = skey[i + 2], s3 = skey[i + 3];
        acc += p1[(size_t)s0 * 64 + l];
        acc += p1[(size_t)s1 * 64 + l];
        acc += p1[(size_t)s2 * 64 + l];
        acc += p1[(size_t)s3 * 64 + l];
    }
    for (; i < end; ++i) acc += p1[(size_t)skey[i] * 64 + l];
    float inv = (dc > 0) ? 1.f / (float)dc : 0.f;
    float h = fmaxf(acc * inv + r1[(size_t)n * 64 + l] + b1[l], 0.f);

    float pv[NC], rv[NC];
#pragma unroll
    for (int c = 0; c < NC; ++c) {
        float a = h * W2l[c * 64 + l];
        float b = h * W2r[c * 64 + l];
#pragma unroll
        for (int d = 32; d; d >>= 1) {
            a += __shfl_xor(a, d);
            b += __shfl_xor(b, d);
        }
        pv[c] = a; rv[c] = b;
    }
    float po = 0.f, ro = 0.f;
#pragma unroll
    for (int c = 0; c < NC; ++c) {
        po = (l == c) ? pv[c] : po;
        ro = (l == c) ? rv[c] : ro;
    }
    if (l < NC) {
        p2[(size_t)n * NC + l] = po;
        r2[(size_t)n * NC + l] = ro;
    }
}

// ---- agg2 + bias + log_softmax fused: 8 lanes per node (lane 7 idle) ----
__global__ __launch_bounds__(256) void k_agg2f(const float* __restrict__ p2,
                                               const float* __restrict__ r2,
                                               const int* __restrict__ skey,
                                               const int* __restrict__ offs,
                                               const int* __restrict__ cnti,
                                               const float* __restrict__ b2,
                                               float* __restrict__ out) {
    int tid = blockIdx.x * 256 + threadIdx.x;
    int n = tid >> 3;
    int c = tid & 7;
    if (n >= NN) return;
    bool act = (c < NC);
    int off = offs[n];
    int dc = cnti[n];
    int i = off, end = off + dc;
    float acc = 0.f;
    for (; i + 3 < end; i += 4) {
        int s0 = skey[i], s1 = skey[i + 1], s2 = skey[i + 2], s3 = skey[i + 3];
        if (act) {
            acc += p2[(size_t)s0 * NC + c];
            acc += p2[(size_t)s1 * NC + c];
            acc += p2[(size_t)s2 * NC + c];
            acc += p2[(size_t)s3 * NC + c];
        }
    }
    for (; i < end; ++i) if (act) acc += p2[(size_t)skey[i] * NC + c];
    float inv = (dc > 0) ? 1.f / (float)dc : 0.f;
    float v = act ? (acc * inv + r2[(size_t)n * NC + c] + b2[c]) : -INFINITY;
    float m = v;
#pragma unroll
    for (int d = 1; d < 8; d <<= 1) m = fmaxf(m, __shfl_xor(m, d));
    float ev = act ? expf(v - m) : 0.f;
    float s = ev;
#pragma unroll
    for (int d = 1; d < 8; d <<= 1) s += __shfl_xor(s, d);
    if (act) out[(size_t)n * NC + c] = v - m - logf(s);
}

extern "C" void kernel_launch(void* const* d_in, const int* in_sizes, int n_in,
                              void* d_out, int out_size, void* d_ws, size_t ws_size,
                              hipStream_t stream) {
    const float* x   = (const float*)d_in[0];
    const int*   ei  = (const int*)d_in[1];   // [2, NE] int32
    const float* W1l = (const float*)d_in[2];
    const float* W1r = (const float*)d_in[3];
    const float* b1  = (const float*)d_in[4];
    const float* W2l = (const float*)d_in[5];
    const float* W2r = (const float*)d_in[6];
    const float* b2  = (const float*)d_in[7];
    float* out = (float*)d_out;

    const int* src = ei;
    const int* dst = ei + NE;

    // workspace layout (4-byte units)
    int* cnti = (int*)d_ws;             // NN
    int* offs = cnti + NN;              // NN
    int* cur  = offs + NN;              // NN
    int* bsum = cur + NN;               // 512
    int* boff = bsum + 512;             // 512
    int* skey = boff + 512;             // NE
    float* Wt = (float*)(skey + NE);    // 128*128
    float* p1 = Wt + 128 * 128;         // NN*64
    float* r1 = p1 + (size_t)NN * HID;  // NN*64
    float* p2 = r1 + (size_t)NN * HID;  // NN*7
    float* r2 = p2 + (size_t)NN * NC;   // NN*7

    hipMemsetAsync(cnti, 0, (size_t)NN * sizeof(int), stream);

    k_hist <<<(NE + 255) / 256, 256, 0, stream>>>(dst, cnti);
    k_bsum <<<NB, 256, 0, stream>>>(cnti, bsum);
    k_bscan<<<1, 512, 0, stream>>>(bsum, boff);
    k_scan3<<<NB, 256, 0, stream>>>(cnti, boff, offs, cur);
    k_sort <<<(NE + 255) / 256, 256, 0, stream>>>(src, dst, cur, skey);
    k_wt   <<<64, 256, 0, stream>>>(W1l, W1r, Wt);
    k_proj1<<<(NN + 127) / 128, 256, 0, stream>>>(x, Wt, p1, r1);
    k_agg1c<<<(NN * 64 + 255) / 256, 256, 0, stream>>>(p1, r1, skey, offs, cnti,
                                                       b1, W2l, W2r, p2, r2);
    k_agg2f<<<(NN * 8 + 255) / 256, 256, 0, stream>>>(p2, r2, skey, offs, cnti,
                                                      b2, out);
}

// Round 4
// 309.902 us; speedup vs baseline: 4.5480x; 2.0049x over previous
//
#include <hip/hip_runtime.h>
#include <math.h>

#define NN 100000
#define NE 3200000
#define FIN 128
#define HID 64
#define NC 7
#define BW 512                    // bucket width (nodes)
#define NBUC 196                  // ceil(NN/BW)
#define CHUNK 8192                // edges staged per block in pass A
#define NCHUNK ((NE + CHUNK - 1) / CHUNK)   // 391

// ---- bucket histogram: gsz[b] = #edges with dst in bucket b (LDS-aggregated)
__global__ __launch_bounds__(256) void k_bhist(const int* __restrict__ dst,
                                               int* __restrict__ gsz) {
    __shared__ int h[NBUC];
    int t = threadIdx.x;
    for (int i = t; i < NBUC; i += 256) h[i] = 0;
    __syncthreads();
    int base = blockIdx.x * CHUNK;
    int cnt = min(CHUNK, NE - base);
    for (int i = t; i < cnt; i += 256)
        atomicAdd(&h[dst[base + i] >> 9], 1);
    __syncthreads();
    for (int i = t; i < NBUC; i += 256)
        if (h[i]) atomicAdd(&gsz[i], h[i]);
}

// ---- exclusive scan of bucket sizes (1 block); init bucket cursors --------
__global__ __launch_bounds__(256) void k_bscan(const int* __restrict__ gsz,
                                               int* __restrict__ gbase,
                                               int* __restrict__ gcur) {
    __shared__ int s[256];
    int t = threadIdx.x;
    int v = (t < NBUC) ? gsz[t] : 0;
    s[t] = v;
    __syncthreads();
    for (int d = 1; d < 256; d <<= 1) {
        int a = (t >= d) ? s[t - d] : 0;
        __syncthreads();
        s[t] += a;
        __syncthreads();
    }
    if (t < NBUC) {
        gbase[t] = s[t] - v;
        gcur[t]  = s[t] - v;
    }
    if (t == NBUC - 1) gbase[NBUC] = s[t];   // = NE
}

// ---- pass A: bucket-scatter packed edges with dense writes ----------------
// pay = (dst&511)<<17 | src  (26 bits)
__global__ __launch_bounds__(256) void k_passA(const int* __restrict__ src,
                                               const int* __restrict__ dst,
                                               int* __restrict__ gcur,
                                               unsigned int* __restrict__ ebuf) {
    __shared__ unsigned int pay[CHUNK];
    __shared__ unsigned char buc[CHUNK];
    __shared__ int h[NBUC];
    __shared__ int lcur[NBUC];
    int t = threadIdx.x;
    for (int i = t; i < NBUC; i += 256) h[i] = 0;
    __syncthreads();
    int base = blockIdx.x * CHUNK;
    int cnt = min(CHUNK, NE - base);
    for (int i = t; i < cnt; i += 256) {
        int s = src[base + i];
        int d = dst[base + i];
        int b = d >> 9;
        pay[i] = ((unsigned)(d & 511) << 17) | (unsigned)s;
        buc[i] = (unsigned char)b;
        atomicAdd(&h[b], 1);
    }
    __syncthreads();
    for (int i = t; i < NBUC; i += 256)
        lcur[i] = h[i] ? atomicAdd(&gcur[i], h[i]) : 0;
    __syncthreads();
    for (int i = t; i < cnt; i += 256) {
        int p = atomicAdd(&lcur[buc[i]], 1);
        ebuf[p] = pay[i];
    }
}

// ---- pass B: per bucket -> per-node counts, offsets (coalesced), skey -----
__global__ __launch_bounds__(512) void k_passB(const unsigned int* __restrict__ ebuf,
                                               const int* __restrict__ gbase,
                                               int* __restrict__ offs,
                                               int* __restrict__ cnti,
                                               int* __restrict__ skey) {
    __shared__ int lcnt[BW];
    __shared__ int lcur[BW];
    __shared__ int s2[256];
    int b = blockIdx.x, t = threadIdx.x;
    int beg = gbase[b], end = gbase[b + 1];
    lcnt[t] = 0;
    __syncthreads();
    for (int i = beg + t; i < end; i += 512)
        atomicAdd(&lcnt[ebuf[i] >> 17], 1);
    __syncthreads();
    int c0 = 0, c1 = 0;
    if (t < 256) {
        c0 = lcnt[2 * t];
        c1 = lcnt[2 * t + 1];
        s2[t] = c0 + c1;
    }
    __syncthreads();
    for (int d = 1; d < 256; d <<= 1) {
        int a = 0;
        if (t < 256 && t >= d) a = s2[t - d];
        __syncthreads();
        if (t < 256) s2[t] += a;
        __syncthreads();
    }
    if (t < 256) {
        int excl = s2[t] - (c0 + c1);
        int o0 = beg + excl;
        int o1 = o0 + c0;
        lcur[2 * t] = o0;
        lcur[2 * t + 1] = o1;
        int n0 = b * BW + 2 * t;
        if (n0 < NN)     { offs[n0] = o0;     cnti[n0] = c0; }
        if (n0 + 1 < NN) { offs[n0 + 1] = o1; cnti[n0 + 1] = c1; }
    }
    __syncthreads();
    for (int i = beg + t; i < end; i += 512) {
        unsigned v = ebuf[i];
        int p = atomicAdd(&lcur[v >> 17], 1);
        skey[p] = (int)(v & 0x1FFFFu);
    }
}

// ---------------- W transpose: Wt[k][j] = (j<64 ? Wl[j][k] : Wr[j-64][k]) ---
__global__ __launch_bounds__(256) void k_wt(const float* __restrict__ Wl,
                                            const float* __restrict__ Wr,
                                            float* __restrict__ Wt) {
    int t = blockIdx.x * 256 + threadIdx.x;
    if (t < 128 * 128) {
        int k = t >> 7, j = t & 127;
        Wt[t] = (j < 64) ? Wl[j * 128 + k] : Wr[(j - 64) * 128 + k];
    }
}

// ---------------- proj1: register-tiled SGEMM ----------------
__global__ __launch_bounds__(256) void k_proj1(const float* __restrict__ x,
                                               const float* __restrict__ Wt,
                                               float* __restrict__ p1,
                                               float* __restrict__ r1) {
    __shared__ float xs[16][132];
    __shared__ float ws[16][128];
    int t = threadIdx.x;
    int tm = t >> 4;
    int tn = t & 15;
    int n0 = blockIdx.x * 128;

    float acc[8][8];
#pragma unroll
    for (int i = 0; i < 8; ++i)
#pragma unroll
        for (int j = 0; j < 8; ++j) acc[i][j] = 0.f;

    for (int k0 = 0; k0 < 128; k0 += 16) {
#pragma unroll
        for (int p = 0; p < 2; ++p) {
            int fid = p * 256 + t;
            int node = fid >> 2;
            int q = fid & 3;
            float4 v = make_float4(0.f, 0.f, 0.f, 0.f);
            if (n0 + node < NN)
                v = *(const float4*)&x[(size_t)(n0 + node) * 128 + k0 + q * 4];
            xs[q * 4 + 0][node] = v.x;
            xs[q * 4 + 1][node] = v.y;
            xs[q * 4 + 2][node] = v.z;
            xs[q * 4 + 3][node] = v.w;
        }
#pragma unroll
        for (int p = 0; p < 2; ++p) {
            int fid = p * 256 + t;
            int kk = fid >> 5;
            int jq = fid & 31;
            *(float4*)&ws[kk][jq * 4] =
                *(const float4*)&Wt[(size_t)(k0 + kk) * 128 + jq * 4];
        }
        __syncthreads();
#pragma unroll
        for (int kk = 0; kk < 16; ++kk) {
            float4 a0 = *(const float4*)&xs[kk][tm * 8];
            float4 a1 = *(const float4*)&xs[kk][tm * 8 + 4];
            float4 b0 = *(const float4*)&ws[kk][tn * 8];
            float4 b1 = *(const float4*)&ws[kk][tn * 8 + 4];
            float a[8] = {a0.x, a0.y, a0.z, a0.w, a1.x, a1.y, a1.z, a1.w};
            float b[8] = {b0.x, b0.y, b0.z, b0.w, b1.x, b1.y, b1.z, b1.w};
#pragma unroll
            for (int i = 0; i < 8; ++i)
#pragma unroll
                for (int j = 0; j < 8; ++j)
                    acc[i][j] = fmaf(a[i], b[j], acc[i][j]);
        }
        __syncthreads();
    }
#pragma unroll
    for (int i = 0; i < 8; ++i) {
        int n = n0 + tm * 8 + i;
        if (n >= NN) break;
        float4 v0 = make_float4(acc[i][0], acc[i][1], acc[i][2], acc[i][3]);
        float4 v1 = make_float4(acc[i][4], acc[i][5], acc[i][6], acc[i][7]);
        if (tn < 8) {
            *(float4*)&p1[(size_t)n * 64 + tn * 8]     = v0;
            *(float4*)&p1[(size_t)n * 64 + tn * 8 + 4] = v1;
        } else {
            *(float4*)&r1[(size_t)n * 64 + (tn - 8) * 8]     = v0;
            *(float4*)&r1[(size_t)n * 64 + (tn - 8) * 8 + 4] = v1;
        }
    }
}

// ---- agg1 + combine1 + proj2 fused: wave per node, lane = channel ----
__global__ __launch_bounds__(256) void k_agg1c(const float* __restrict__ p1,
                                               const float* __restrict__ r1,
                                               const int* __restrict__ skey,
                                               const int* __restrict__ offs,
                                               const int* __restrict__ cnti,
                                               const float* __restrict__ b1,
                                               const float* __restrict__ W2l,
                                               const float* __restrict__ W2r,
                                               float* __restrict__ p2,
                                               float* __restrict__ r2) {
    int n = (blockIdx.x * 256 + threadIdx.x) >> 6;
    int l = threadIdx.x & 63;
    if (n >= NN) return;
    int off = offs[n];
    int dc = cnti[n];
    int i = off, end = off + dc;
    float acc = 0.f;
    for (; i + 3 < end; i += 4) {
        int s0 = skey[i], s1 = skey[i + 1], s2 = skey[i + 2], s3 = skey[i + 3];
        acc += p1[(size_t)s0 * 64 + l];
        acc += p1[(size_t)s1 * 64 + l];
        acc += p1[(size_t)s2 * 64 + l];
        acc += p1[(size_t)s3 * 64 + l];
    }
    for (; i < end; ++i) acc += p1[(size_t)skey[i] * 64 + l];
    float inv = (dc > 0) ? 1.f / (float)dc : 0.f;
    float h = fmaxf(acc * inv + r1[(size_t)n * 64 + l] + b1[l], 0.f);

    float pv[NC], rv[NC];
#pragma unroll
    for (int c = 0; c < NC; ++c) {
        float a = h * W2l[c * 64 + l];
        float b = h * W2r[c * 64 + l];
#pragma unroll
        for (int d = 32; d; d >>= 1) {
            a += __shfl_xor(a, d);
            b += __shfl_xor(b, d);
        }
        pv[c] = a; rv[c] = b;
    }
    float po = 0.f, ro = 0.f;
#pragma unroll
    for (int c = 0; c < NC; ++c) {
        po = (l == c) ? pv[c] : po;
        ro = (l == c) ? rv[c] : ro;
    }
    if (l < NC) {
        p2[(size_t)n * NC + l] = po;
        r2[(size_t)n * NC + l] = ro;
    }
}

// ---- agg2 + bias + log_softmax fused: 8 lanes per node (lane 7 idle) ----
__global__ __launch_bounds__(256) void k_agg2f(const float* __restrict__ p2,
                                               const float* __restrict__ r2,
                                               const int* __restrict__ skey,
                                               const int* __restrict__ offs,
                                               const int* __restrict__ cnti,
                                               const float* __restrict__ b2,
                                               float* __restrict__ out) {
    int tid = blockIdx.x * 256 + threadIdx.x;
    int n = tid >> 3;
    int c = tid & 7;
    if (n >= NN) return;
    bool act = (c < NC);
    int off = offs[n];
    int dc = cnti[n];
    int i = off, end = off + dc;
    float acc = 0.f;
    for (; i + 3 < end; i += 4) {
        int s0 = skey[i], s1 = skey[i + 1], s2 = skey[i + 2], s3 = skey[i + 3];
        if (act) {
            acc += p2[(size_t)s0 * NC + c];
            acc += p2[(size_t)s1 * NC + c];
            acc += p2[(size_t)s2 * NC + c];
            acc += p2[(size_t)s3 * NC + c];
        }
    }
    for (; i < end; ++i) if (act) acc += p2[(size_t)skey[i] * NC + c];
    float inv = (dc > 0) ? 1.f / (float)dc : 0.f;
    float v = act ? (acc * inv + r2[(size_t)n * NC + c] + b2[c]) : -INFINITY;
    float m = v;
#pragma unroll
    for (int d = 1; d < 8; d <<= 1) m = fmaxf(m, __shfl_xor(m, d));
    float ev = act ? expf(v - m) : 0.f;
    float s = ev;
#pragma unroll
    for (int d = 1; d < 8; d <<= 1) s += __shfl_xor(s, d);
    if (act) out[(size_t)n * NC + c] = v - m - logf(s);
}

extern "C" void kernel_launch(void* const* d_in, const int* in_sizes, int n_in,
                              void* d_out, int out_size, void* d_ws, size_t ws_size,
                              hipStream_t stream) {
    const float* x   = (const float*)d_in[0];
    const int*   ei  = (const int*)d_in[1];   // [2, NE] int32
    const float* W1l = (const float*)d_in[2];
    const float* W1r = (const float*)d_in[3];
    const float* b1  = (const float*)d_in[4];
    const float* W2l = (const float*)d_in[5];
    const float* W2r = (const float*)d_in[6];
    const float* b2  = (const float*)d_in[7];
    float* out = (float*)d_out;

    const int* src = ei;
    const int* dst = ei + NE;

    // workspace layout (4-byte units), total ~83.3 MB
    int* gsz   = (int*)d_ws;                // 256
    int* gbase = gsz + 256;                 // 256 (NBUC+1 used)
    int* gcur  = gbase + 256;               // 256
    int* cnti  = gcur + 256;                // NN
    int* offs  = cnti + NN;                 // NN
    unsigned int* ebuf = (unsigned int*)(offs + NN);  // NE
    int* skey  = (int*)(ebuf + NE);         // NE
    float* Wt  = (float*)(skey + NE);       // 128*128
    float* p1  = Wt + 128 * 128;            // NN*64
    float* r1  = p1 + (size_t)NN * HID;     // NN*64
    float* p2  = r1 + (size_t)NN * HID;     // NN*7
    float* r2  = p2 + (size_t)NN * NC;      // NN*7

    hipMemsetAsync(gsz, 0, NBUC * sizeof(int), stream);

    k_bhist<<<NCHUNK, 256, 0, stream>>>(dst, gsz);
    k_bscan<<<1, 256, 0, stream>>>(gsz, gbase, gcur);
    k_passA<<<NCHUNK, 256, 0, stream>>>(src, dst, gcur, ebuf);
    k_passB<<<NBUC, 512, 0, stream>>>(ebuf, gbase, offs, cnti, skey);
    k_wt   <<<64, 256, 0, stream>>>(W1l, W1r, Wt);
    k_proj1<<<(NN + 127) / 128, 256, 0, stream>>>(x, Wt, p1, r1);
    k_agg1c<<<(NN * 64 + 255) / 256, 256, 0, stream>>>(p1, r1, skey, offs, cnti,
                                                       b1, W2l, W2r, p2, r2);
    k_agg2f<<<(NN * 8 + 255) / 256, 256, 0, stream>>>(p2, r2, skey, offs, cnti,
                                                      b2, out);
}

// Round 5
// 293.349 us; speedup vs baseline: 4.8046x; 1.0564x over previous
//
#include <hip/hip_runtime.h>
#include <math.h>

#define NN 100000
#define NE 3200000
#define FIN 128
#define HID 64
#define NC 7
#define BW 512                    // bucket width (nodes)
#define NBUC 196                  // ceil(NN/BW)
#define CHUNK 8192                // edges staged per block in pass A
#define NCHUNK ((NE + CHUNK - 1) / CHUNK)   // 391

__device__ __forceinline__ unsigned int f2bf(float x) {
    unsigned int u = __float_as_uint(x);
    return (u + 0x7fffu + ((u >> 16) & 1u)) >> 16;   // RTNE
}

// ---- bucket histogram: gsz[b] = #edges with dst in bucket b (LDS-aggregated)
__global__ __launch_bounds__(256) void k_bhist(const int* __restrict__ dst,
                                               int* __restrict__ gsz) {
    __shared__ int h[NBUC];
    int t = threadIdx.x;
    for (int i = t; i < NBUC; i += 256) h[i] = 0;
    __syncthreads();
    int base = blockIdx.x * CHUNK;
    int cnt = min(CHUNK, NE - base);
    for (int i = t; i < cnt; i += 256)
        atomicAdd(&h[dst[base + i] >> 9], 1);
    __syncthreads();
    for (int i = t; i < NBUC; i += 256)
        if (h[i]) atomicAdd(&gsz[i], h[i]);
}

// ---- exclusive scan of bucket sizes (1 block); init bucket cursors --------
__global__ __launch_bounds__(256) void k_bscan(const int* __restrict__ gsz,
                                               int* __restrict__ gbase,
                                               int* __restrict__ gcur) {
    __shared__ int s[256];
    int t = threadIdx.x;
    int v = (t < NBUC) ? gsz[t] : 0;
    s[t] = v;
    __syncthreads();
    for (int d = 1; d < 256; d <<= 1) {
        int a = (t >= d) ? s[t - d] : 0;
        __syncthreads();
        s[t] += a;
        __syncthreads();
    }
    if (t < NBUC) {
        gbase[t] = s[t] - v;
        gcur[t]  = s[t] - v;
    }
    if (t == NBUC - 1) gbase[NBUC] = s[t];   // = NE
}

// ---- pass A: bucket-scatter packed edges with dense writes ----------------
// pay = (dst&511)<<17 | src  (26 bits)
__global__ __launch_bounds__(256) void k_passA(const int* __restrict__ src,
                                               const int* __restrict__ dst,
                                               int* __restrict__ gcur,
                                               unsigned int* __restrict__ ebuf) {
    __shared__ unsigned int pay[CHUNK];
    __shared__ unsigned char buc[CHUNK];
    __shared__ int h[NBUC];
    __shared__ int lcur[NBUC];
    int t = threadIdx.x;
    for (int i = t; i < NBUC; i += 256) h[i] = 0;
    __syncthreads();
    int base = blockIdx.x * CHUNK;
    int cnt = min(CHUNK, NE - base);
    for (int i = t; i < cnt; i += 256) {
        int s = src[base + i];
        int d = dst[base + i];
        int b = d >> 9;
        pay[i] = ((unsigned)(d & 511) << 17) | (unsigned)s;
        buc[i] = (unsigned char)b;
        atomicAdd(&h[b], 1);
    }
    __syncthreads();
    for (int i = t; i < NBUC; i += 256)
        lcur[i] = h[i] ? atomicAdd(&gcur[i], h[i]) : 0;
    __syncthreads();
    for (int i = t; i < cnt; i += 256) {
        int p = atomicAdd(&lcur[buc[i]], 1);
        ebuf[p] = pay[i];
    }
}

// ---- pass B: per bucket -> per-node counts, offsets (coalesced), skey -----
__global__ __launch_bounds__(512) void k_passB(const unsigned int* __restrict__ ebuf,
                                               const int* __restrict__ gbase,
                                               int* __restrict__ offs,
                                               int* __restrict__ cnti,
                                               int* __restrict__ skey) {
    __shared__ int lcnt[BW];
    __shared__ int lcur[BW];
    __shared__ int s2[256];
    int b = blockIdx.x, t = threadIdx.x;
    int beg = gbase[b], end = gbase[b + 1];
    lcnt[t] = 0;
    __syncthreads();
    for (int i = beg + t; i < end; i += 512)
        atomicAdd(&lcnt[ebuf[i] >> 17], 1);
    __syncthreads();
    int c0 = 0, c1 = 0;
    if (t < 256) {
        c0 = lcnt[2 * t];
        c1 = lcnt[2 * t + 1];
        s2[t] = c0 + c1;
    }
    __syncthreads();
    for (int d = 1; d < 256; d <<= 1) {
        int a = 0;
        if (t < 256 && t >= d) a = s2[t - d];
        __syncthreads();
        if (t < 256) s2[t] += a;
        __syncthreads();
    }
    if (t < 256) {
        int excl = s2[t] - (c0 + c1);
        int o0 = beg + excl;
        int o1 = o0 + c0;
        lcur[2 * t] = o0;
        lcur[2 * t + 1] = o1;
        int n0 = b * BW + 2 * t;
        if (n0 < NN)     { offs[n0] = o0;     cnti[n0] = c0; }
        if (n0 + 1 < NN) { offs[n0 + 1] = o1; cnti[n0 + 1] = c1; }
    }
    __syncthreads();
    for (int i = beg + t; i < end; i += 512) {
        unsigned v = ebuf[i];
        int p = atomicAdd(&lcur[v >> 17], 1);
        skey[p] = (int)(v & 0x1FFFFu);
    }
}

// ---------------- W transpose: Wt[k][j] = (j<64 ? Wl[j][k] : Wr[j-64][k]) ---
__global__ __launch_bounds__(256) void k_wt(const float* __restrict__ Wl,
                                            const float* __restrict__ Wr,
                                            float* __restrict__ Wt) {
    int t = blockIdx.x * 256 + threadIdx.x;
    if (t < 128 * 128) {
        int k = t >> 7, j = t & 127;
        Wt[t] = (j < 64) ? Wl[j * 128 + k] : Wr[(j - 64) * 128 + k];
    }
}

// ---------------- proj1: register-tiled SGEMM ----------------
// p1 stored as packed bf16 pairs: p1b[n*32 + i] = (bf16(ch 2i), bf16(ch 2i+1))
__global__ __launch_bounds__(256) void k_proj1(const float* __restrict__ x,
                                               const float* __restrict__ Wt,
                                               unsigned int* __restrict__ p1b,
                                               float* __restrict__ r1) {
    __shared__ float xs[16][132];
    __shared__ float ws[16][128];
    int t = threadIdx.x;
    int tm = t >> 4;
    int tn = t & 15;
    int n0 = blockIdx.x * 128;

    float acc[8][8];
#pragma unroll
    for (int i = 0; i < 8; ++i)
#pragma unroll
        for (int j = 0; j < 8; ++j) acc[i][j] = 0.f;

    for (int k0 = 0; k0 < 128; k0 += 16) {
#pragma unroll
        for (int p = 0; p < 2; ++p) {
            int fid = p * 256 + t;
            int node = fid >> 2;
            int q = fid & 3;
            float4 v = make_float4(0.f, 0.f, 0.f, 0.f);
            if (n0 + node < NN)
                v = *(const float4*)&x[(size_t)(n0 + node) * 128 + k0 + q * 4];
            xs[q * 4 + 0][node] = v.x;
            xs[q * 4 + 1][node] = v.y;
            xs[q * 4 + 2][node] = v.z;
            xs[q * 4 + 3][node] = v.w;
        }
#pragma unroll
        for (int p = 0; p < 2; ++p) {
            int fid = p * 256 + t;
            int kk = fid >> 5;
            int jq = fid & 31;
            *(float4*)&ws[kk][jq * 4] =
                *(const float4*)&Wt[(size_t)(k0 + kk) * 128 + jq * 4];
        }
        __syncthreads();
#pragma unroll
        for (int kk = 0; kk < 16; ++kk) {
            float4 a0 = *(const float4*)&xs[kk][tm * 8];
            float4 a1 = *(const float4*)&xs[kk][tm * 8 + 4];
            float4 b0 = *(const float4*)&ws[kk][tn * 8];
            float4 b1 = *(const float4*)&ws[kk][tn * 8 + 4];
            float a[8] = {a0.x, a0.y, a0.z, a0.w, a1.x, a1.y, a1.z, a1.w};
            float b[8] = {b0.x, b0.y, b0.z, b0.w, b1.x, b1.y, b1.z, b1.w};
#pragma unroll
            for (int i = 0; i < 8; ++i)
#pragma unroll
                for (int j = 0; j < 8; ++j)
                    acc[i][j] = fmaf(a[i], b[j], acc[i][j]);
        }
        __syncthreads();
    }
#pragma unroll
    for (int i = 0; i < 8; ++i) {
        int n = n0 + tm * 8 + i;
        if (n >= NN) break;
        if (tn < 8) {
            // p1 channels tn*8 .. tn*8+7 -> 4 packed uints at p1b[n*32+tn*4]
            uint4 u;
            u.x = f2bf(acc[i][0]) | (f2bf(acc[i][1]) << 16);
            u.y = f2bf(acc[i][2]) | (f2bf(acc[i][3]) << 16);
            u.z = f2bf(acc[i][4]) | (f2bf(acc[i][5]) << 16);
            u.w = f2bf(acc[i][6]) | (f2bf(acc[i][7]) << 16);
            *(uint4*)&p1b[(size_t)n * 32 + tn * 4] = u;
        } else {
            float4 v0 = make_float4(acc[i][0], acc[i][1], acc[i][2], acc[i][3]);
            float4 v1 = make_float4(acc[i][4], acc[i][5], acc[i][6], acc[i][7]);
            *(float4*)&r1[(size_t)n * 64 + (tn - 8) * 8]     = v0;
            *(float4*)&r1[(size_t)n * 64 + (tn - 8) * 8 + 4] = v1;
        }
    }
}

// ---- agg1 + combine1 + proj2 fused: wave per node ----
// Lanes 0-31 process even edges, 32-63 odd edges; each lane loads one uint
// (2 bf16 channels). Combine via shfl_xor(32), redistribute via 2 shfls.
__global__ __launch_bounds__(256) void k_agg1c(const unsigned int* __restrict__ p1b,
                                               const float* __restrict__ r1,
                                               const int* __restrict__ skey,
                                               const int* __restrict__ offs,
                                               const int* __restrict__ cnti,
                                               const float* __restrict__ b1,
                                               const float* __restrict__ W2l,
                                               const float* __restrict__ W2r,
                                               float* __restrict__ p2,
                                               float* __restrict__ r2) {
    int n = (blockIdx.x * 256 + threadIdx.x) >> 6;
    int l = threadIdx.x & 63;
    if (n >= NN) return;
    int half = l >> 5;      // 0: even edges, 1: odd edges
    int i32 = l & 31;       // channel-pair index
    int off = offs[n];
    int dc = cnti[n];
    float a0 = 0.f, a1 = 0.f;
    int e = half;
    for (; e + 2 < dc; e += 4) {
        int s0 = skey[off + e];
        int s1 = skey[off + e + 2];
        unsigned v0 = p1b[(size_t)s0 * 32 + i32];
        unsigned v1 = p1b[(size_t)s1 * 32 + i32];
        a0 += __uint_as_float(v0 << 16);
        a1 += __uint_as_float(v0 & 0xffff0000u);
        a0 += __uint_as_float(v1 << 16);
        a1 += __uint_as_float(v1 & 0xffff0000u);
    }
    for (; e < dc; e += 2) {
        int s0 = skey[off + e];
        unsigned v0 = p1b[(size_t)s0 * 32 + i32];
        a0 += __uint_as_float(v0 << 16);
        a1 += __uint_as_float(v0 & 0xffff0000u);
    }
    // combine even/odd halves
    a0 += __shfl_xor(a0, 32);
    a1 += __shfl_xor(a1, 32);
    // redistribute: lane l wants channel l = pair (l>>1), component (l&1)
    float ca = __shfl(a0, l >> 1);
    float cb = __shfl(a1, l >> 1);
    float acc = (l & 1) ? cb : ca;

    float inv = (dc > 0) ? 1.f / (float)dc : 0.f;
    float h = fmaxf(acc * inv + r1[(size_t)n * 64 + l] + b1[l], 0.f);

    float pv[NC], rv[NC];
#pragma unroll
    for (int c = 0; c < NC; ++c) {
        float a = h * W2l[c * 64 + l];
        float b = h * W2r[c * 64 + l];
#pragma unroll
        for (int d = 32; d; d >>= 1) {
            a += __shfl_xor(a, d);
            b += __shfl_xor(b, d);
        }
        pv[c] = a; rv[c] = b;
    }
    float po = 0.f, ro = 0.f;
#pragma unroll
    for (int c = 0; c < NC; ++c) {
        po = (l == c) ? pv[c] : po;
        ro = (l == c) ? rv[c] : ro;
    }
    if (l < NC) {
        p2[(size_t)n * NC + l] = po;
        r2[(size_t)n * NC + l] = ro;
    }
}

// ---- agg2 + bias + log_softmax fused: 8 lanes per node (lane 7 idle) ----
__global__ __launch_bounds__(256) void k_agg2f(const float* __restrict__ p2,
                                               const float* __restrict__ r2,
                                               const int* __restrict__ skey,
                                               const int* __restrict__ offs,
                                               const int* __restrict__ cnti,
                                               const float* __restrict__ b2,
                                               float* __restrict__ out) {
    int tid = blockIdx.x * 256 + threadIdx.x;
    int n = tid >> 3;
    int c = tid & 7;
    if (n >= NN) return;
    bool act = (c < NC);
    int off = offs[n];
    int dc = cnti[n];
    int i = off, end = off + dc;
    float acc = 0.f;
    for (; i + 3 < end; i += 4) {
        int s0 = skey[i], s1 = skey[i + 1], s2 = skey[i + 2], s3 = skey[i + 3];
        if (act) {
            acc += p2[(size_t)s0 * NC + c];
            acc += p2[(size_t)s1 * NC + c];
            acc += p2[(size_t)s2 * NC + c];
            acc += p2[(size_t)s3 * NC + c];
        }
    }
    for (; i < end; ++i) if (act) acc += p2[(size_t)skey[i] * NC + c];
    float inv = (dc > 0) ? 1.f / (float)dc : 0.f;
    float v = act ? (acc * inv + r2[(size_t)n * NC + c] + b2[c]) : -INFINITY;
    float m = v;
#pragma unroll
    for (int d = 1; d < 8; d <<= 1) m = fmaxf(m, __shfl_xor(m, d));
    float ev = act ? expf(v - m) : 0.f;
    float s = ev;
#pragma unroll
    for (int d = 1; d < 8; d <<= 1) s += __shfl_xor(s, d);
    if (act) out[(size_t)n * NC + c] = v - m - logf(s);
}

extern "C" void kernel_launch(void* const* d_in, const int* in_sizes, int n_in,
                              void* d_out, int out_size, void* d_ws, size_t ws_size,
                              hipStream_t stream) {
    const float* x   = (const float*)d_in[0];
    const int*   ei  = (const int*)d_in[1];   // [2, NE] int32
    const float* W1l = (const float*)d_in[2];
    const float* W1r = (const float*)d_in[3];
    const float* b1  = (const float*)d_in[4];
    const float* W2l = (const float*)d_in[5];
    const float* W2r = (const float*)d_in[6];
    const float* b2  = (const float*)d_in[7];
    float* out = (float*)d_out;

    const int* src = ei;
    const int* dst = ei + NE;

    // workspace layout (4-byte units)
    int* gsz   = (int*)d_ws;                // 256
    int* gbase = gsz + 256;                 // 256 (NBUC+1 used)
    int* gcur  = gbase + 256;               // 256
    int* cnti  = gcur + 256;                // NN
    int* offs  = cnti + NN;                 // NN
    unsigned int* ebuf = (unsigned int*)(offs + NN);  // NE
    int* skey  = (int*)(ebuf + NE);         // NE
    float* Wt  = (float*)(skey + NE);       // 128*128
    unsigned int* p1b = (unsigned int*)(Wt + 128 * 128);  // NN*32
    float* r1  = (float*)(p1b + (size_t)NN * 32);         // NN*64
    float* p2  = r1 + (size_t)NN * HID;     // NN*7
    float* r2  = p2 + (size_t)NN * NC;      // NN*7

    hipMemsetAsync(gsz, 0, NBUC * sizeof(int), stream);

    k_bhist<<<NCHUNK, 256, 0, stream>>>(dst, gsz);
    k_bscan<<<1, 256, 0, stream>>>(gsz, gbase, gcur);
    k_passA<<<NCHUNK, 256, 0, stream>>>(src, dst, gcur, ebuf);
    k_passB<<<NBUC, 512, 0, stream>>>(ebuf, gbase, offs, cnti, skey);
    k_wt   <<<64, 256, 0, stream>>>(W1l, W1r, Wt);
    k_proj1<<<(NN + 127) / 128, 256, 0, stream>>>(x, Wt, p1b, r1);
    k_agg1c<<<(NN * 64 + 255) / 256, 256, 0, stream>>>(p1b, r1, skey, offs, cnti,
                                                       b1, W2l, W2r, p2, r2);
    k_agg2f<<<(NN * 8 + 255) / 256, 256, 0, stream>>>(p2, r2, skey, offs, cnti,
                                                      b2, out);
}